// Round 4
// baseline (61.815 us; speedup 1.0000x reference)
//
#include <hip/hip_runtime.h>
#include <hip/hip_cooperative_groups.h>

namespace cg = cooperative_groups;

// EqFrePBC: frequency-domain perturbation compensation, single cooperative kernel.
// B=2, L=2048, N=2 modes, pairs = full 40x40 grid (n1,n2 in [-20,19]).
//   G[b,m,d]    = sum_n xf[b,m,n]*conj(xf[b,(m-(d-20))%L,n])
//   S2[b,d,l]   = sum_{n1i} w[n1i,d] * G[b,(l-(n1i-20))%L,d]
//   dfreq[b,n,l]= sum_d S2[b,d,l] * xf[b,n,(l-(d-20))%L]
// Bias is constant over freq -> IFFT puts it only at t=0, cropped out.
// P1: fwd-FFT (blocks 0-3) + zero df | sync
// P2: fused G+S2+deltaf-scatter (160 blocks, fp32 atomics into df) | sync
// P3: IFFT + epilogue (blocks 0-3)

#define L_FFT 2048
#define NB 2
#define NM 2
#define ND 40
#define CROP 20
#define LOUT 2008
#define NBLK 160
#define NT 1024
#define TILE 1024
#define SLAB 1103   // TILE + 79
#define GSZ 1063    // TILE + 39

__device__ __forceinline__ float2 cmul(float2 a, float2 b) {
    return make_float2(a.x*b.x - a.y*b.y, a.x*b.y + a.y*b.x);
}
__device__ __forceinline__ float2 cmulc(float2 a, float2 b) {  // a * conj(b)
    return make_float2(a.x*b.x + a.y*b.y, a.y*b.x - a.x*b.y);
}

// tw[t] = exp(SIGN * i * 2*pi*t/2048), t in [0,1024)
template<int SIGN>
__device__ void build_tw(float2* tw, int tid) {
    for (int t = tid; t < 1024; t += NT) {
        float ang = (float)(SIGN * t) * 3.0679615757712823e-03f;  // 2*pi/2048
        tw[t] = make_float2(__cosf(ang), __sinf(ang));
    }
}

// Radix-2 Stockham autosort FFT, 2048 points, NT threads, table twiddles.
__device__ float2* fft2048(float2* bufA, float2* bufB, const float2* tw, int tid) {
    float2* src = bufA;
    float2* dst = bufB;
    int m = 1;
    for (int stage = 0; stage < 11; ++stage) {
        __syncthreads();
        {
            int q = tid;
            int k = q & (m - 1);
            int jm = q - k;                 // j*m, twiddle index
            float2 w = tw[jm];
            float2 a = src[q];
            float2 b = src[q + 1024];
            float2 dif = make_float2(a.x - b.x, a.y - b.y);
            dst[2*jm + k]     = make_float2(a.x + b.x, a.y + b.y);
            dst[2*jm + k + m] = make_float2(dif.x*w.x - dif.y*w.y, dif.x*w.y + dif.y*w.x);
        }
        float2* t = src; src = dst; dst = t;
        m <<= 1;
    }
    __syncthreads();
    return src;   // 11 stages (odd) -> result lands in bufB
}

__global__ __launch_bounds__(NT) void fused_kernel(const float* __restrict__ xr,
                                                   const float* __restrict__ xi,
                                                   const float* __restrict__ task,
                                                   const float* __restrict__ wr,
                                                   const float* __restrict__ wi,
                                                   float* __restrict__ out,
                                                   float2* __restrict__ xf,
                                                   float* __restrict__ df) {
    cg::grid_group grid = cg::this_grid();
    __shared__ float2 sm[5120];        // 40 KB, re-purposed per phase
    __shared__ float wrs[ND], wis[ND];
    int blk = blockIdx.x;
    int tid = threadIdx.x;

    // ---------------- P1: forward FFT for (b,n) = blk, blocks 0-3 ----------------
    if (blk < NB * NM) {
        int b = blk >> 1, n = blk & 1;
        float2* bufA = sm;
        float2* bufB = sm + 2048;
        float2* tw   = sm + 4096;
        // zero this (b,n)'s dfreq slice for P2's atomic accumulation
        float2* dfv = (float2*)df + blk * L_FFT;
        #pragma unroll
        for (int i = 0; i < 2; ++i)
            dfv[tid + i * NT] = make_float2(0.f, 0.f);
        for (int t = tid; t < L_FFT; t += NT) {
            int gi = (b * L_FFT + t) * NM + n;
            bufA[t] = make_float2(xr[gi], xi[gi]);
        }
        build_tw<-1>(tw, tid);
        float2* res = fft2048(bufA, bufB, tw, tid);
        for (int f = tid; f < L_FFT; f += NT)
            xf[blk * L_FFT + f] = res[f];
    }
    grid.sync();

    // ---------------- P2: G + S2 + deltaf-scatter, one (b, d, l-tile) per block --
    {
        int b   = blk / 80;
        int rem = blk % 80;
        int d   = rem >> 1;            // n2 index, 0..39
        int l0  = (rem & 1) << 10;     // l-tile origin (0 or 1024)
        int dd  = d - 20;
        float2* xs0 = sm;
        float2* xs1 = sm + SLAB;
        float2* Gs  = sm + 2 * SLAB;
        const float2* x0 = xf + (b * 2 + 0) * L_FFT;
        const float2* x1 = xf + (b * 2 + 1) * L_FFT;
        for (int i = tid; i < SLAB; i += NT) {
            int m = (l0 - 39 + i) & (L_FFT - 1);
            xs0[i] = x0[m];
            xs1[i] = x1[m];
        }
        if (tid < ND) { wrs[tid] = wr[tid * ND + d]; wis[tid] = wi[tid * ND + d]; }
        __syncthreads();
        // Gs[j] = G[b, l0-19+j, d], j in [0, GSZ)
        for (int j = tid; j < GSZ; j += NT) {
            float2 g0 = cmulc(xs0[j + 20], xs0[j + 20 - dd]);
            float2 g1 = cmulc(xs1[j + 20], xs1[j + 20 - dd]);
            Gs[j] = make_float2(g0.x + g1.x, g0.y + g1.y);
        }
        __syncthreads();
        // S2[l0+tid] = sum_{n1i} w[n1i,d] * G[l-(n1i-20)] -> Gs[tid + 39 - n1i]
        float2 acc = make_float2(0.f, 0.f);
        #pragma unroll
        for (int n1i = 0; n1i < ND; ++n1i) {
            float2 g = Gs[tid + 39 - n1i];
            float wxr = wrs[n1i], wxi = wis[n1i];
            acc.x += wxr * g.x - wxi * g.y;
            acc.y += wxr * g.y + wxi * g.x;
        }
        // deltaf scatter: df[b,n,l] += S2 * xf[b,n,l-dd] = S2 * xs[n][tid+39-dd]
        int xvi  = tid + 39 - dd;
        int base = (b * 2) * (L_FFT * 2) + (l0 + tid) * 2;
        float2 c0 = cmul(acc, xs0[xvi]);
        unsafeAtomicAdd(&df[base + 0], c0.x);
        unsafeAtomicAdd(&df[base + 1], c0.y);
        float2 c1 = cmul(acc, xs1[xvi]);
        unsafeAtomicAdd(&df[base + L_FFT * 2 + 0], c1.x);
        unsafeAtomicAdd(&df[base + L_FFT * 2 + 1], c1.y);
    }
    grid.sync();

    // ---------------- P3: inverse FFT + epilogue, blocks 0-3 ---------------------
    if (blk < NB * NM) {
        int b = blk >> 1, n = blk & 1;
        float2* bufA = sm;
        float2* bufB = sm + 2048;
        float2* tw   = sm + 4096;
        const float2* dfreq = (const float2*)df + blk * L_FFT;
        for (int i = tid; i < L_FFT; i += NT)
            bufA[i] = dfreq[i];
        build_tw<1>(tw, tid);
        float2* res = fft2048(bufA, bufB, tw, tid);
        float P = 1e-3f * __powf(10.f, task[b * 4] * 0.1f) * 0.5f;   // /N with N=2
        float scale = P * (1.0f / (float)L_FFT);                     // fold ifft 1/L
        for (int t = CROP + tid; t < L_FFT - CROP; t += NT) {
            int gi = (b * L_FFT + t) * NM + n;
            float2 dv = res[t];
            int oi = ((b * LOUT + (t - CROP)) * NM + n) * 2;
            out[oi]     = xr[gi] + dv.x * scale;
            out[oi + 1] = xi[gi] + dv.y * scale;
        }
    }
}

extern "C" void kernel_launch(void* const* d_in, const int* in_sizes, int n_in,
                              void* d_out, int out_size, void* d_ws, size_t ws_size,
                              hipStream_t stream) {
    const float* xr   = (const float*)d_in[0];
    const float* xi   = (const float*)d_in[1];
    const float* task = (const float*)d_in[2];
    const float* wr   = (const float*)d_in[3];
    const float* wi   = (const float*)d_in[4];
    // d_in[5], d_in[6]: fc_br / fc_bi -- bias lands only at t=0 after IFFT, cropped out.
    float* out = (float*)d_out;

    float2* ws = (float2*)d_ws;
    float2* xf = ws;                    // 8192 float2  [b*2+n][l]
    float*  df = (float*)(ws + 8192);   // 16384 float  [b*2+n][l][2], atomic-accumulated

    void* args[] = { (void*)&xr, (void*)&xi, (void*)&task, (void*)&wr, (void*)&wi,
                     (void*)&out, (void*)&xf, (void*)&df };
    hipLaunchCooperativeKernel((void*)fused_kernel, dim3(NBLK), dim3(NT), args, 0, stream);
}

// Round 5
// 40.819 us; speedup vs baseline: 1.5144x; 1.5144x over previous
//
#include <hip/hip_runtime.h>

// EqFrePBC: frequency-domain perturbation compensation, single kernel + custom grid barrier.
// B=2, L=2048, N=2 modes, pairs = full 40x40 grid (n1,n2 in [-20,19]).
//   G[b,m,d]    = sum_n xf[b,m,n]*conj(xf[b,(m-(d-20))%L,n])
//   S2[b,d,l]   = sum_{n1i} w[n1i,d] * G[b,(l-(n1i-20))%L,d]
//   dfreq[b,n,l]= sum_d S2[b,d,l] * xf[b,n,(l-(d-20))%L]
// Bias is constant over freq -> IFFT puts it only at t=0, cropped out.
// Launch 0: hipMemsetAsync zeroes df + barrier counters (graph-capturable).
// Launch 1 (160 blk x 1024): P1 fwd-FFT (blocks 0-3) | barrier |
//   P2 G+S2+deltaf-scatter (fp32 device atomics into df) | barrier |
//   P3 IFFT + epilogue (blocks 0-3).
// Custom barrier: threadfence (agent release, L2 wb) -> atomicAdd -> relaxed spin
// -> threadfence (acquire, inv). 160 blocks co-resident (2 blk/CU capacity).

#define L_FFT 2048
#define NB 2
#define NM 2
#define ND 40
#define CROP 20
#define LOUT 2008
#define NBLK 160
#define NT 1024
#define SLAB 1103   // 1024 + 79
#define GSZ 1063    // 1024 + 39

__device__ __forceinline__ float2 cmul(float2 a, float2 b) {
    return make_float2(a.x*b.x - a.y*b.y, a.x*b.y + a.y*b.x);
}
__device__ __forceinline__ float2 cmulc(float2 a, float2 b) {  // a * conj(b)
    return make_float2(a.x*b.x + a.y*b.y, a.y*b.x - a.x*b.y);
}

__device__ __forceinline__ void grid_barrier(int* cnt) {
    __syncthreads();
    if (threadIdx.x == 0) {
        __threadfence();   // agent-scope release: write back local L2
        __hip_atomic_fetch_add(cnt, 1, __ATOMIC_ACQ_REL, __HIP_MEMORY_SCOPE_AGENT);
        while (__hip_atomic_load(cnt, __ATOMIC_RELAXED, __HIP_MEMORY_SCOPE_AGENT) < NBLK)
            __builtin_amdgcn_s_sleep(1);
        __threadfence();   // agent-scope acquire: invalidate stale cache
    }
    __syncthreads();
}

// tw[t] = exp(SIGN * i * 2*pi*t/2048), t in [0,1024)
template<int SIGN>
__device__ void build_tw(float2* tw, int tid) {
    for (int t = tid; t < 1024; t += NT) {
        float ang = (float)(SIGN * t) * 3.0679615757712823e-03f;  // 2*pi/2048
        tw[t] = make_float2(__cosf(ang), __sinf(ang));
    }
}

// Radix-2 Stockham autosort FFT, 2048 points, NT=1024 threads, table twiddles.
__device__ float2* fft2048(float2* bufA, float2* bufB, const float2* tw, int tid) {
    float2* src = bufA;
    float2* dst = bufB;
    int m = 1;
    for (int stage = 0; stage < 11; ++stage) {
        __syncthreads();
        {
            int q = tid;
            int k = q & (m - 1);
            int jm = q - k;                 // j*m, twiddle index
            float2 w = tw[jm];
            float2 a = src[q];
            float2 b = src[q + 1024];
            float2 dif = make_float2(a.x - b.x, a.y - b.y);
            dst[2*jm + k]     = make_float2(a.x + b.x, a.y + b.y);
            dst[2*jm + k + m] = make_float2(dif.x*w.x - dif.y*w.y, dif.x*w.y + dif.y*w.x);
        }
        float2* t = src; src = dst; dst = t;
        m <<= 1;
    }
    __syncthreads();
    return src;   // 11 stages (odd) -> result lands in bufB
}

__global__ __launch_bounds__(NT) void fused_kernel(const float* __restrict__ xr,
                                                   const float* __restrict__ xi,
                                                   const float* __restrict__ task,
                                                   const float* __restrict__ wr,
                                                   const float* __restrict__ wi,
                                                   float* __restrict__ out,
                                                   float2* __restrict__ xf,
                                                   float* __restrict__ df,
                                                   int* __restrict__ cnt) {
    __shared__ float2 sm[5120];        // 40 KB, re-purposed per phase
    __shared__ float wrs[ND], wis[ND];
    int blk = blockIdx.x;
    int tid = threadIdx.x;

    // ---------------- P1: forward FFT for (b,n) = blk, blocks 0-3 ----------------
    if (blk < NB * NM) {
        int b = blk >> 1, n = blk & 1;
        float2* bufA = sm;
        float2* bufB = sm + 2048;
        float2* tw   = sm + 4096;
        for (int t = tid; t < L_FFT; t += NT) {
            int gi = (b * L_FFT + t) * NM + n;
            bufA[t] = make_float2(xr[gi], xi[gi]);
        }
        build_tw<-1>(tw, tid);
        float2* res = fft2048(bufA, bufB, tw, tid);
        for (int f = tid; f < L_FFT; f += NT)
            xf[blk * L_FFT + f] = res[f];
    }
    grid_barrier(&cnt[0]);

    // ---------------- P2: G + S2 + deltaf-scatter, one (b, d, l-tile) per block --
    {
        int b   = blk / 80;
        int rem = blk % 80;
        int d   = rem >> 1;            // n2 index, 0..39
        int l0  = (rem & 1) << 10;     // l-tile origin (0 or 1024)
        int dd  = d - 20;
        float2* xs0 = sm;
        float2* xs1 = sm + SLAB;
        float2* Gs  = sm + 2 * SLAB;
        const float2* x0 = xf + (b * 2 + 0) * L_FFT;
        const float2* x1 = xf + (b * 2 + 1) * L_FFT;
        for (int i = tid; i < SLAB; i += NT) {
            int m = (l0 - 39 + i) & (L_FFT - 1);
            xs0[i] = x0[m];
            xs1[i] = x1[m];
        }
        if (tid < ND) { wrs[tid] = wr[tid * ND + d]; wis[tid] = wi[tid * ND + d]; }
        __syncthreads();
        // Gs[j] = G[b, l0-19+j, d], j in [0, GSZ)
        for (int j = tid; j < GSZ; j += NT) {
            float2 g0 = cmulc(xs0[j + 20], xs0[j + 20 - dd]);
            float2 g1 = cmulc(xs1[j + 20], xs1[j + 20 - dd]);
            Gs[j] = make_float2(g0.x + g1.x, g0.y + g1.y);
        }
        __syncthreads();
        // S2[l0+tid] = sum_{n1i} w[n1i,d] * G[l-(n1i-20)] -> Gs[tid + 39 - n1i]
        float2 acc = make_float2(0.f, 0.f);
        #pragma unroll
        for (int n1i = 0; n1i < ND; ++n1i) {
            float2 g = Gs[tid + 39 - n1i];
            float wxr = wrs[n1i], wxi = wis[n1i];
            acc.x += wxr * g.x - wxi * g.y;
            acc.y += wxr * g.y + wxi * g.x;
        }
        // deltaf scatter: df[b,n,l] += S2 * xf[b,n,l-dd] = S2 * xs[n][tid+39-dd]
        int xvi  = tid + 39 - dd;
        int base = (b * 2) * (L_FFT * 2) + (l0 + tid) * 2;
        float2 c0 = cmul(acc, xs0[xvi]);
        unsafeAtomicAdd(&df[base + 0], c0.x);
        unsafeAtomicAdd(&df[base + 1], c0.y);
        float2 c1 = cmul(acc, xs1[xvi]);
        unsafeAtomicAdd(&df[base + L_FFT * 2 + 0], c1.x);
        unsafeAtomicAdd(&df[base + L_FFT * 2 + 1], c1.y);
    }
    grid_barrier(&cnt[16]);

    // ---------------- P3: inverse FFT + epilogue, blocks 0-3 ---------------------
    if (blk < NB * NM) {
        int b = blk >> 1, n = blk & 1;
        float2* bufA = sm;
        float2* bufB = sm + 2048;
        float2* tw   = sm + 4096;
        const float2* dfreq = (const float2*)df + blk * L_FFT;
        for (int i = tid; i < L_FFT; i += NT)
            bufA[i] = dfreq[i];
        build_tw<1>(tw, tid);
        float2* res = fft2048(bufA, bufB, tw, tid);
        float P = 1e-3f * __powf(10.f, task[b * 4] * 0.1f) * 0.5f;   // /N with N=2
        float scale = P * (1.0f / (float)L_FFT);                     // fold ifft 1/L
        for (int t = CROP + tid; t < L_FFT - CROP; t += NT) {
            int gi = (b * L_FFT + t) * NM + n;
            float2 dv = res[t];
            int oi = ((b * LOUT + (t - CROP)) * NM + n) * 2;
            out[oi]     = xr[gi] + dv.x * scale;
            out[oi + 1] = xi[gi] + dv.y * scale;
        }
    }
}

extern "C" void kernel_launch(void* const* d_in, const int* in_sizes, int n_in,
                              void* d_out, int out_size, void* d_ws, size_t ws_size,
                              hipStream_t stream) {
    const float* xr   = (const float*)d_in[0];
    const float* xi   = (const float*)d_in[1];
    const float* task = (const float*)d_in[2];
    const float* wr   = (const float*)d_in[3];
    const float* wi   = (const float*)d_in[4];
    // d_in[5], d_in[6]: fc_br / fc_bi -- bias lands only at t=0 after IFFT, cropped out.
    float* out = (float*)d_out;

    float2* ws = (float2*)d_ws;
    float2* xf = ws;                         // 8192 float2  [b*2+n][l]
    float*  df = (float*)(ws + 8192);        // 16384 float  [b*2+n][l][2], atomic-accumulated
    int*    cnt = (int*)(ws + 8192 + 8192);  // barrier counters (2 cells, 64B apart)

    // Zero df + counters every call (ws is poisoned once, never re-poisoned).
    hipMemsetAsync((void*)df, 0, 16384 * sizeof(float) + 128, stream);

    void* kargs[] = { (void*)&xr, (void*)&xi, (void*)&task, (void*)&wr, (void*)&wi,
                      (void*)&out, (void*)&xf, (void*)&df, (void*)&cnt };
    hipLaunchKernelGGL(fused_kernel, dim3(NBLK), dim3(NT), 0, stream,
                       xr, xi, task, wr, wi, out, xf, df, cnt);
    (void)kargs;
}

// Round 6
// 23.015 us; speedup vs baseline: 2.6859x; 1.7736x over previous
//
#include <hip/hip_runtime.h>

// EqFrePBC: frequency-domain perturbation compensation. 3-kernel graph (kernel
// boundaries are the cheapest grid barrier; measured: cg grid.sync ~15us/sync,
// custom fence+spin barrier ~13us/sync, kernel boundary ~free).
// B=2, L=2048, N=2 modes, pairs = full 40x40 grid (n1,n2 in [-20,19]).
//   G[b,m,d]    = sum_n xf[b,m,n]*conj(xf[b,(m-(d-20))%L,n])
//   S2[b,d,l]   = sum_{n1i} w[n1i,d] * G[b,(l-(n1i-20))%L,d]
//   dfreq[b,n,l]= sum_d S2[b,d,l] * xf[b,n,(l-(d-20))%L]
// Bias is constant over freq -> IFFT puts it only at t=0, cropped out.
// K1: fwd radix-4 FFT (4 blk x 512) + zero df
// K2: G+S2+deltaf-scatter, d-quad per block (160 blk x 256): 164K atomics (4x fewer)
// K3: radix-4 IFFT + epilogue (4 blk x 512)

#define L_FFT 2048
#define NB 2
#define NM 2
#define ND 40
#define CROP 20
#define LOUT 2008

__device__ __forceinline__ float2 cmul(float2 a, float2 b) {
    return make_float2(a.x*b.x - a.y*b.y, a.x*b.y + a.y*b.x);
}
__device__ __forceinline__ float2 cmulc(float2 a, float2 b) {  // a * conj(b)
    return make_float2(a.x*b.x + a.y*b.y, a.y*b.x - a.x*b.y);
}

// tw[t] = exp(SIGN * i * 2*pi*t/2048), t in [0,512)
template<int SIGN>
__device__ void build_tw(float2* tw, int tid) {
    if (tid < 512) {
        float ang = (float)(SIGN * tid) * 3.0679615757712823e-03f;  // 2*pi/2048
        tw[tid] = make_float2(__cosf(ang), __sinf(ang));
    }
}

// Radix-4 Stockham FFT, 2048 pts, 512 threads. Derived by composing the
// (validated) radix-2 Stockham stages (m,2m) -> radix-4 stage, m in {1,4,16,64,256},
// then one trivial radix-2 stage (m=1024). Result lands back in bufA.
// sigma = w^512 = SIGN*i folds the D-path half-turn twiddle.
template<int SIGN>
__device__ float2* fft2048_r4(float2* bufA, float2* bufB, const float2* tw, int tid) {
    float2* src = bufA;
    float2* dst = bufB;
    #pragma unroll
    for (int m = 1; m <= 256; m *= 4) {
        __syncthreads();
        int k2 = tid & (m - 1);
        int jm = tid - k2;                     // m*j2, < 512
        float2 A = src[tid];
        float2 C = src[tid + 512];
        float2 B = src[tid + 1024];
        float2 D = src[tid + 1536];
        float2 T0 = make_float2(A.x + B.x, A.y + B.y);
        float2 T1 = make_float2(A.x - B.x, A.y - B.y);
        float2 T2 = make_float2(C.x + D.x, C.y + D.y);
        float2 cd = make_float2(C.x - D.x, C.y - D.y);
        float2 T3 = (SIGN < 0) ? make_float2(cd.y, -cd.x)    // -i*(C-D)
                               : make_float2(-cd.y, cd.x);   // +i*(C-D)
        float2 w1 = tw[jm];
        float2 w2 = cmul(w1, w1);
        float2 w3 = cmul(w2, w1);
        int base = 4 * jm + k2;
        dst[base]         = make_float2(T0.x + T2.x, T0.y + T2.y);
        dst[base + m]     = cmul(make_float2(T1.x + T3.x, T1.y + T3.y), w1);
        dst[base + 2*m]   = cmul(make_float2(T0.x - T2.x, T0.y - T2.y), w2);
        dst[base + 3*m]   = cmul(make_float2(T1.x - T3.x, T1.y - T3.y), w3);
        float2* t = src; src = dst; dst = t;
    }
    __syncthreads();
    // final radix-2 stage, m=1024: twiddle w^0 = 1
    #pragma unroll
    for (int it = 0; it < 2; ++it) {
        int q = tid + it * 512;
        float2 a = src[q];
        float2 b = src[q + 1024];
        dst[q]        = make_float2(a.x + b.x, a.y + b.y);
        dst[q + 1024] = make_float2(a.x - b.x, a.y - b.y);
    }
    float2* res = dst;
    __syncthreads();
    return res;
}

__global__ __launch_bounds__(512) void fft_fwd_kernel(const float* __restrict__ xr,
                                                      const float* __restrict__ xi,
                                                      float2* __restrict__ xf,
                                                      float* __restrict__ df) {
    __shared__ float2 bufA[L_FFT];
    __shared__ float2 bufB[L_FFT];
    __shared__ float2 tw[512];
    int bn = blockIdx.x;            // b*2 + n
    int b = bn >> 1, n = bn & 1;
    int tid = threadIdx.x;
    // zero this (b,n)'s dfreq slice for K2's atomic accumulation
    #pragma unroll
    for (int i = 0; i < 8; ++i)
        df[bn * (L_FFT * 2) + tid + i * 512] = 0.f;
    #pragma unroll
    for (int it = 0; it < 4; ++it) {
        int t = tid + it * 512;
        int gi = (b * L_FFT + t) * NM + n;
        bufA[t] = make_float2(xr[gi], xi[gi]);
    }
    build_tw<-1>(tw, tid);
    float2* res = fft2048_r4<-1>(bufA, bufB, tw, tid);
    #pragma unroll
    for (int it = 0; it < 4; ++it) {
        int f = tid + it * 512;
        xf[bn * L_FFT + f] = res[f];
    }
}

// Fused G + S2 + deltaf-scatter. One block per (b, d-quad, l-tile of 256).
__global__ __launch_bounds__(256) void gs2_kernel(const float2* __restrict__ xf,
                                                  const float* __restrict__ wr,
                                                  const float* __restrict__ wi,
                                                  float* __restrict__ df) {
    __shared__ float2 xs0[336], xs1[336];
    __shared__ float2 Gs[296];
    __shared__ float wrs[40][4], wis[40][4];   // [n1i][di]
    int blk = blockIdx.x;
    int b   = blk / 80;
    int rem = blk % 80;
    int dq  = rem >> 3;          // d-quad index, 0..9
    int l0  = (rem & 7) << 8;    // l-tile origin
    int tid = threadIdx.x;
    const float2* x0 = xf + (b * 2 + 0) * L_FFT;
    const float2* x1 = xf + (b * 2 + 1) * L_FFT;
    for (int i = tid; i < 336; i += 256) {
        int m = (l0 - 39 + i) & (L_FFT - 1);
        xs0[i] = x0[m];
        xs1[i] = x1[m];
    }
    if (tid < 160) {
        int n1i = tid >> 2, di = tid & 3;
        wrs[n1i][di] = wr[n1i * ND + dq * 4 + di];
        wis[n1i][di] = wi[n1i * ND + dq * 4 + di];
    }
    __syncthreads();
    float2 a0 = make_float2(0.f, 0.f);   // df accum, mode 0
    float2 a1 = make_float2(0.f, 0.f);   // df accum, mode 1
    #pragma unroll
    for (int di = 0; di < 4; ++di) {
        int d  = dq * 4 + di;
        int dd = d - 20;
        // Gs[j] = G[b, l0-19+j, d], j in [0,295)
        for (int j = tid; j < 295; j += 256) {
            float2 g0 = cmulc(xs0[j + 20], xs0[j + 20 - dd]);
            float2 g1 = cmulc(xs1[j + 20], xs1[j + 20 - dd]);
            Gs[j] = make_float2(g0.x + g1.x, g0.y + g1.y);
        }
        __syncthreads();
        // S2 = sum_{n1i} w[n1i,d] * Gs[tid + 39 - n1i]
        float2 acc = make_float2(0.f, 0.f);
        #pragma unroll
        for (int n1i = 0; n1i < ND; ++n1i) {
            float2 g = Gs[tid + 39 - n1i];
            float wxr = wrs[n1i][di], wxi = wis[n1i][di];
            acc.x += wxr * g.x - wxi * g.y;
            acc.y += wxr * g.y + wxi * g.x;
        }
        // accumulate deltaf contribution: S2 * xf[b,n,l-dd] = S2 * xs[n][tid+39-dd]
        int xvi = tid + 39 - dd;
        float2 c0 = cmul(acc, xs0[xvi]);
        float2 c1 = cmul(acc, xs1[xvi]);
        a0.x += c0.x; a0.y += c0.y;
        a1.x += c1.x; a1.y += c1.y;
        __syncthreads();   // before Gs overwrite next di
    }
    int base = (b * 2) * (L_FFT * 2) + (l0 + tid) * 2;
    unsafeAtomicAdd(&df[base + 0], a0.x);
    unsafeAtomicAdd(&df[base + 1], a0.y);
    unsafeAtomicAdd(&df[base + L_FFT * 2 + 0], a1.x);
    unsafeAtomicAdd(&df[base + L_FFT * 2 + 1], a1.y);
}

// IFFT + epilogue. One block per (b,n).
__global__ __launch_bounds__(512) void ifft_out_kernel(const float* __restrict__ df,
                                                       const float* __restrict__ xr,
                                                       const float* __restrict__ xi,
                                                       const float* __restrict__ task,
                                                       float* __restrict__ out) {
    __shared__ float2 bufA[L_FFT];
    __shared__ float2 bufB[L_FFT];
    __shared__ float2 tw[512];
    int bn = blockIdx.x;            // b*2 + n
    int b = bn >> 1, n = bn & 1;
    int tid = threadIdx.x;
    const float2* dfreq = (const float2*)df + bn * L_FFT;
    #pragma unroll
    for (int it = 0; it < 4; ++it)
        bufA[tid + it * 512] = dfreq[tid + it * 512];
    build_tw<1>(tw, tid);
    float2* res = fft2048_r4<1>(bufA, bufB, tw, tid);
    float P = 1e-3f * __powf(10.f, task[b * 4] * 0.1f) * 0.5f;   // /N with N=2
    float scale = P * (1.0f / (float)L_FFT);                     // fold ifft 1/L
    for (int t = CROP + tid; t < L_FFT - CROP; t += 512) {
        int gi = (b * L_FFT + t) * NM + n;
        float2 dv = res[t];
        int oi = ((b * LOUT + (t - CROP)) * NM + n) * 2;
        out[oi]     = xr[gi] + dv.x * scale;
        out[oi + 1] = xi[gi] + dv.y * scale;
    }
}

extern "C" void kernel_launch(void* const* d_in, const int* in_sizes, int n_in,
                              void* d_out, int out_size, void* d_ws, size_t ws_size,
                              hipStream_t stream) {
    const float* xr   = (const float*)d_in[0];
    const float* xi   = (const float*)d_in[1];
    const float* task = (const float*)d_in[2];
    const float* wr   = (const float*)d_in[3];
    const float* wi   = (const float*)d_in[4];
    // d_in[5], d_in[6]: fc_br / fc_bi -- bias lands only at t=0 after IFFT, cropped out.
    float* out = (float*)d_out;

    float2* ws = (float2*)d_ws;
    float2* xf = ws;                    // 8192 float2  [b*2+n][l]
    float*  df = (float*)(ws + 8192);   // 16384 float  [b*2+n][l][2], atomic-accumulated

    hipLaunchKernelGGL(fft_fwd_kernel,  dim3(NB * NM), dim3(512), 0, stream, xr, xi, xf, df);
    hipLaunchKernelGGL(gs2_kernel,      dim3(160), dim3(256), 0, stream, xf, wr, wi, df);
    hipLaunchKernelGGL(ifft_out_kernel, dim3(NB * NM), dim3(512), 0, stream, df, xr, xi, task, out);
}